// Round 8
// baseline (112.518 us; speedup 1.0000x reference)
//
#include <hip/hip_runtime.h>
#include <math.h>

#define S_LEN 2048
#define HID   768
#define NH    12
#define HD    64
#define WIN   128
#define NEGV  (-1e30f)
#define QSCALE 0.1803368801111204f   /* 0.125 * log2(e): scores in log2 domain */
#define NROW  49152                  /* B*NH*S = 2*12*2048 */

typedef __attribute__((ext_vector_type(8))) short short8v;
typedef __attribute__((ext_vector_type(4))) float float4v;
typedef unsigned short u16;

__device__ __forceinline__ u16 f2bf(float f) {
    union { float f; unsigned int u; } c; c.f = f;
    unsigned int u = c.u + 0x7FFFu + ((c.u >> 16) & 1u);
    return (u16)(u >> 16);
}

__device__ __forceinline__ short8v cvt8(float4 a, float4 b) {
    short8v t;
    t[0]=(short)f2bf(a.x); t[1]=(short)f2bf(a.y); t[2]=(short)f2bf(a.z); t[3]=(short)f2bf(a.w);
    t[4]=(short)f2bf(b.x); t[5]=(short)f2bf(b.y); t[6]=(short)f2bf(b.z); t[7]=(short)f2bf(b.w);
    return t;
}

__device__ __forceinline__ unsigned int pk2bf(float a, float b) {
    unsigned int r;
    asm("v_cvt_pk_bf16_f32 %0, %1, %2" : "=v"(r) : "v"(a), "v"(b));
    return r;
}

__device__ __forceinline__ float exp2_fast(float x) {
    float r;
    asm("v_exp_f32 %0, %1" : "=v"(r) : "v"(x));
    return r;
}

__device__ __forceinline__ short8v mk8(unsigned a, unsigned b, unsigned c, unsigned d) {
    union { short8v v; unsigned u[4]; } t;
    t.u[0]=a; t.u[1]=b; t.u[2]=c; t.u[3]=d; return t.v;
}

__device__ __forceinline__ float bf2f(u16 v) {
    union { float f; unsigned u; } c; c.u = ((unsigned)v) << 16; return c.f;
}

__device__ __forceinline__ void gload_lds16(const void* g, void* l) {
    __builtin_amdgcn_global_load_lds(
        (const __attribute__((address_space(1))) unsigned int*)g,
        (__attribute__((address_space(3))) unsigned int*)l, 16, 0, 0);
}

// ---------------------------------------------------------------------------
// Convert hidden + 4 weights to bf16 (Wq scaled by 0.125*log2e).
// ---------------------------------------------------------------------------
__global__ __launch_bounds__(256) void convert_inputs(
    const float* __restrict__ hidden, const float* __restrict__ Wq,
    const float* __restrict__ Wk, const float* __restrict__ Wv,
    const float* __restrict__ Wo, u16* __restrict__ hbf, u16* __restrict__ w4)
{
    const int y = blockIdx.y;
    const float* src; u16* dst; int n; float scale = 1.f;
    if (y == 0) { src = hidden; dst = hbf; n = 4096*HID; }
    else {
        src = (y==1) ? Wq : (y==2) ? Wk : (y==3) ? Wv : Wo;
        dst = w4 + (size_t)(y-1)*HID*HID;
        n = HID*HID;
        if (y == 1) scale = QSCALE;
    }
    const int idx = (blockIdx.x*256 + threadIdx.x) * 8;
    if (idx >= n) return;
    float4 f0 = *(const float4*)(src + idx);
    float4 f1 = *(const float4*)(src + idx + 4);
    f0.x*=scale; f0.y*=scale; f0.z*=scale; f0.w*=scale;
    f1.x*=scale; f1.y*=scale; f1.z*=scale; f1.w*=scale;
    *(short8v*)(dst + idx) = cvt8(f0, f1);
}

// ---------------------------------------------------------------------------
// bf16 MFMA GEMM (m97 structure). C[m][n] = sum_k A[m][k]*W[n][k] + bias[n].
// mode 0: z in {0,1,2}. z=0,1 (Q,K): out bf16 (B,nh,S,hd) at obf + z*NTOK.
//         z=2 (V): out bf16 TRANSPOSED (B,nh,hd,S) at ovt.
// mode 1: Wo; out f32 flat (B,S,H).
// ---------------------------------------------------------------------------
__global__ __launch_bounds__(256) void gemm_mfma(
    const u16* __restrict__ A, const u16* __restrict__ W4,
    const float* __restrict__ bA, const float* __restrict__ bB,
    const float* __restrict__ bC, u16* __restrict__ obf,
    u16* __restrict__ ovt, float* __restrict__ of32, int mode)
{
    __shared__ __align__(16) u16 As[128*32];
    __shared__ __align__(16) u16 Bs[128*32];

    const int tid = threadIdx.x;
    const int w = tid >> 6, l = tid & 63;
    const int lx = l & 15, lg = l >> 4;
    const int wr = w >> 1, wc = w & 1;
    const int m0 = blockIdx.x * 128, n0 = blockIdx.y * 128;
    const int z = (mode == 0) ? blockIdx.z : 3;
    const float* bias = (mode == 1) ? bA : (z == 0 ? bA : (z == 1 ? bB : bC));
    const float bscale = (mode == 0 && z == 0) ? QSCALE : 1.0f;
    const u16* Wp = W4 + (size_t)z * (HID*HID);

    float4v acc[4][4];
    const float4v fz = {0.f,0.f,0.f,0.f};
    #pragma unroll
    for (int i = 0; i < 4; i++)
        #pragma unroll
        for (int j = 0; j < 4; j++) acc[i][j] = fz;

    for (int kt = 0; kt < HID/32; kt++) {
        const int k0 = kt * 32;
        __syncthreads();
        #pragma unroll
        for (int rnd = 0; rnd < 2; rnd++) {
            const int ch  = rnd*256 + w*64 + l;
            const int row = ch >> 2, kc = ch & 3;
            gload_lds16(A  + (size_t)(m0+row)*HID + k0 + kc*8,
                        As + (size_t)(rnd*256 + w*64)*8);
            gload_lds16(Wp + (size_t)(n0+row)*HID + k0 + kc*8,
                        Bs + (size_t)(rnd*256 + w*64)*8);
        }
        __syncthreads();
        short8v af[4], bfr[4];
        #pragma unroll
        for (int i = 0; i < 4; i++) {
            af[i]  = *(const short8v*)(As + (wr*64 + i*16 + lx)*32 + lg*8);
            bfr[i] = *(const short8v*)(Bs + (wc*64 + i*16 + lx)*32 + lg*8);
        }
        #pragma unroll
        for (int i = 0; i < 4; i++)
            #pragma unroll
            for (int j = 0; j < 4; j++)
                acc[i][j] = __builtin_amdgcn_mfma_f32_16x16x32_bf16(af[i], bfr[j], acc[i][j], 0, 0, 0);
    }

    #pragma unroll
    for (int j = 0; j < 4; j++) {
        const int col = n0 + wc*64 + j*16 + lx;
        const float bval = bias[col] * bscale;
        const int hh = col >> 6, d = col & 63;
        #pragma unroll
        for (int i = 0; i < 4; i++) {
            const int rbase = m0 + wr*64 + i*16 + lg*4;
            const int bb = rbase >> 11, s = rbase & 2047;
            const float v0 = acc[i][j][0] + bval;
            const float v1 = acc[i][j][1] + bval;
            const float v2 = acc[i][j][2] + bval;
            const float v3 = acc[i][j][3] + bval;
            if (mode == 1) {
                of32[(size_t)(rbase+0)*HID + col] = v0;
                of32[(size_t)(rbase+1)*HID + col] = v1;
                of32[(size_t)(rbase+2)*HID + col] = v2;
                of32[(size_t)(rbase+3)*HID + col] = v3;
            } else if (z == 2) {
                uint2 ow; ow.x = pk2bf(v0, v1); ow.y = pk2bf(v2, v3);
                *(uint2*)&ovt[(((size_t)bb*NH + hh)*HD + d)*S_LEN + s] = ow;
            } else {
                u16* base = obf + (size_t)z * ((size_t)2*S_LEN*HID);
                base[(((size_t)bb*NH + hh)*S_LEN + s+0)*HD + d] = f2bf(v0);
                base[(((size_t)bb*NH + hh)*S_LEN + s+1)*HD + d] = f2bf(v1);
                base[(((size_t)bb*NH + hh)*S_LEN + s+2)*HD + d] = f2bf(v2);
                base[(((size_t)bb*NH + hh)*S_LEN + s+3)*HD + d] = f2bf(v3);
            }
        }
    }
}

// ---------------------------------------------------------------------------
// Flash attention, split-K x2. Round 8:
//  - K LDS rows bit-permuted (row x holds key kappa(x), kappa: [b5 b3 b2 b4 b1 b0])
//    so QK's C-layout hands each lane exactly the P values PV's B-frag needs
//    -> P is LANE-LOCAL (no Ps LDS buffer, no round-trip).
//  - Each block does half the keys (16 tiles); writes unnormalized O (bf16) +
//    (m, l) partials. Separate merge kernel combines halves.
//  - Single-buffered K/V LDS (16.5 KB) -> 6 blocks/CU resident.
// ---------------------------------------------------------------------------
__global__ __launch_bounds__(256) void attn_split(
    const u16* __restrict__ Q, const u16* __restrict__ K,
    const u16* __restrict__ Vt, const int* __restrict__ amask,
    const int* __restrict__ gmask, u16* __restrict__ O0,
    u16* __restrict__ O1, float* __restrict__ Mp, float* __restrict__ Lp)
{
    __shared__ __align__(16) u16 Ks[64*64];   // [perm-row][d] swizzled
    __shared__ __align__(16) u16 Vs[64*64];   // [d][key] swizzled
    __shared__ __align__(16) float fA[64];    // am ? 0 : NEG   (natural key idx)
    __shared__ __align__(16) float fB[64];    // am&&gk ? 0 : NEG

    const int tid = threadIdx.x;
    const int w  = tid >> 6;
    const int l  = tid & 63;
    const int lx = l & 15;
    const int lg = l >> 4;

    // XCD swizzle: 1536 = 8 * 192 (bijective). swz = hb*64 + qi*2 + half.
    const int bid = blockIdx.x;
    const int swz = (bid & 7) * 192 + (bid >> 3);
    const int half = swz & 1;
    const int q0 = ((swz >> 1) & 31) * 64;
    const int hb = swz >> 6;
    const int h  = hb % NH;
    const int b  = hb / NH;
    const size_t bh = ((size_t)b*NH + h) * S_LEN;

    const int q_glob = q0 + w*16 + lx;

    short8v aq[2];
    {
        const u16* qp = Q + (bh + q_glob)*HD + lg*8;
        aq[0] = *(const short8v*)(qp);
        aq[1] = *(const short8v*)(qp + 32);
    }
    const int gq = gmask[(size_t)b*S_LEN + q_glob];
    const float* fP = gq ? fA : fB;

    float m_i = NEGV, l_i = 0.f;
    float4v o_acc[4];
    const float4v fzv = {0.f, 0.f, 0.f, 0.f};
    #pragma unroll
    for (int db = 0; db < 4; db++) o_acc[db] = fzv;

    const int str = tid >> 2;        // key (K) / d-row (V), 0..63
    const int stc = tid & 3;
    // K row permutation: row x holds key kappa(x); inverse for staging:
    const int xr  = (str & 32) | (((str>>2)&1)<<4) | (((str>>4)&1)<<3)
                  | (((str>>3)&1)<<2) | (str & 3);
    const int rbK = xr * 128;
    const int swK = (xr & 7) << 4;
    const int rbV = str * 128;
    const int swV = (str & 7) << 4;
    const u16* Kbase = K + bh * HD;
    const u16* Vbase = Vt + (size_t)(b*NH + h) * HD * S_LEN;

    uint4 rk0, rk1, rv0, rv1;
    int ram = 0, rgk = 0;

#define STAGE_REGS(KT) do {                                                   \
    const int kk0_ = (KT) * 64;                                               \
    const u16* kp_ = Kbase + (size_t)(kk0_ + str)*HD + stc*16;                \
    rk0 = *(const uint4*)(kp_); rk1 = *(const uint4*)(kp_ + 8);               \
    const u16* vp_ = Vbase + (size_t)str*S_LEN + kk0_ + stc*16;               \
    rv0 = *(const uint4*)(vp_); rv1 = *(const uint4*)(vp_ + 8);               \
    if (tid < 64) {                                                           \
        ram = amask[(size_t)b*S_LEN + kk0_ + tid];                            \
        rgk = gmask[(size_t)b*S_LEN + kk0_ + tid];                            \
    }                                                                         \
} while(0)

#define WRITE_LDS() do {                                                      \
    *(uint4*)((char*)Ks + rbK + ((stc*32)      ^ swK)) = rk0;                 \
    *(uint4*)((char*)Ks + rbK + ((stc*32 + 16) ^ swK)) = rk1;                 \
    *(uint4*)((char*)Vs + rbV + ((stc*32)      ^ swV)) = rv0;                 \
    *(uint4*)((char*)Vs + rbV + ((stc*32 + 16) ^ swV)) = rv1;                 \
    if (tid < 64) {                                                           \
        fA[tid] = ram ? 0.f : NEGV;                                           \
        fB[tid] = (ram && rgk) ? 0.f : NEGV;                                  \
    }                                                                         \
} while(0)

#define COMPUTE(K0) do {                                                      \
    /* sacc[kb][r] = S[key = 32*(kb>>1) + 8*lg + 4*(kb&1) + r][q=q_glob] */   \
    float4v sacc[4];                                                          \
    const int adq_ = ((K0) > q0) ? ((K0) - q0) : (q0 - (K0));                 \
    if (adq_ <= 64) {                                                         \
        _Pragma("unroll")                                                     \
        for (int kb = 0; kb < 4; kb++) {                                      \
            const int base_ = 32*(kb>>1) + 8*lg + 4*(kb&1);                   \
            float4 fa4 = *(const float4*)&fA[base_];                          \
            sacc[kb][0]=fa4.x; sacc[kb][1]=fa4.y;                             \
            sacc[kb][2]=fa4.z; sacc[kb][3]=fa4.w;                             \
        }                                                                     \
    } else if (adq_ >= 192) {                                                 \
        _Pragma("unroll")                                                     \
        for (int kb = 0; kb < 4; kb++) {                                      \
            const int base_ = 32*(kb>>1) + 8*lg + 4*(kb&1);                   \
            float4 fp4 = *(const float4*)&fP[base_];                          \
            sacc[kb][0]=fp4.x; sacc[kb][1]=fp4.y;                             \
            sacc[kb][2]=fp4.z; sacc[kb][3]=fp4.w;                             \
        }                                                                     \
    } else {                                                                  \
        _Pragma("unroll")                                                     \
        for (int kb = 0; kb < 4; kb++) {                                      \
            const int base_ = 32*(kb>>1) + 8*lg + 4*(kb&1);                   \
            float4 fa4 = *(const float4*)&fA[base_];                          \
            float4 fb4 = *(const float4*)&fB[base_];                          \
            const int e_ = q_glob - ((K0) + base_);                           \
            _Pragma("unroll")                                                 \
            for (int r = 0; r < 4; r++) {                                     \
                int dd_ = e_ - r; dd_ = dd_ < 0 ? -dd_ : dd_;                 \
                const bool wing_ = (dd_ <= WIN) || gq;                        \
                sacc[kb][r] = wing_ ? (&fa4.x)[r] : (&fb4.x)[r];              \
            }                                                                 \
        }                                                                     \
    }                                                                         \
    __builtin_amdgcn_s_setprio(1);                                            \
    _Pragma("unroll")                                                         \
    for (int kb = 0; kb < 4; kb++) {                                          \
        const int row_ = kb*16 + lx;                                          \
        const int ksw_ = (row_ & 7) << 4;                                     \
        _Pragma("unroll")                                                     \
        for (int ks = 0; ks < 2; ks++) {                                      \
            short8v bk_ = *(const short8v*)((char*)Ks + row_*128 +            \
                                            ((16*lg + 64*ks) ^ ksw_));        \
            sacc[kb] = __builtin_amdgcn_mfma_f32_16x16x32_bf16(bk_, aq[ks],   \
                                                          sacc[kb], 0, 0, 0); \
        }                                                                     \
    }                                                                         \
    __builtin_amdgcn_s_setprio(0);                                            \
    float mloc;                                                               \
    {                                                                         \
        float t0 = fmaxf(fmaxf(sacc[0][0], sacc[0][1]), sacc[0][2]);          \
        float t1 = fmaxf(fmaxf(sacc[0][3], sacc[1][0]), sacc[1][1]);          \
        float t2 = fmaxf(fmaxf(sacc[1][2], sacc[1][3]), sacc[2][0]);          \
        float t3 = fmaxf(fmaxf(sacc[2][1], sacc[2][2]), sacc[2][3]);          \
        float t4 = fmaxf(fmaxf(sacc[3][0], sacc[3][1]), sacc[3][2]);          \
        mloc = fmaxf(fmaxf(fmaxf(t0, t1), t2),                                \
                     fmaxf(fmaxf(t3, t4), sacc[3][3]));                       \
    }                                                                         \
    mloc = fmaxf(mloc, __shfl_xor(mloc, 16));                                 \
    mloc = fmaxf(mloc, __shfl_xor(mloc, 32));                                 \
    if (__any(mloc > m_i + 8.0f)) {                                           \
        const float mnew_ = fmaxf(m_i, mloc);                                 \
        const float sc_ = exp2_fast(m_i - mnew_);                             \
        l_i *= sc_;                                                           \
        _Pragma("unroll")                                                     \
        for (int db = 0; db < 4; db++)                                        \
            _Pragma("unroll")                                                 \
            for (int r = 0; r < 4; r++) o_acc[db][r] *= sc_;                  \
        m_i = mnew_;                                                          \
    }                                                                         \
    float p[4][4];                                                            \
    _Pragma("unroll")                                                         \
    for (int kb = 0; kb < 4; kb++)                                            \
        _Pragma("unroll")                                                     \
        for (int r = 0; r < 4; r++)                                           \
            p[kb][r] = exp2_fast(sacc[kb][r] - m_i);                          \
    {                                                                         \
        float s0 = (p[0][0]+p[0][1]) + (p[0][2]+p[0][3]);                     \
        float s1 = (p[1][0]+p[1][1]) + (p[1][2]+p[1][3]);                     \
        float s2 = (p[2][0]+p[2][1]) + (p[2][2]+p[2][3]);                     \
        float s3 = (p[3][0]+p[3][1]) + (p[3][2]+p[3][3]);                     \
        float lsum = (s0+s1) + (s2+s3);                                       \
        lsum += __shfl_xor(lsum, 16);                                         \
        lsum += __shfl_xor(lsum, 32);                                         \
        l_i += lsum;                                                          \
    }                                                                         \
    /* P lane-local: keys 32h+8lg+{0..3} = p[2h][*], +{4..7} = p[2h+1][*] */  \
    __builtin_amdgcn_s_setprio(1);                                            \
    _Pragma("unroll")                                                         \
    for (int hh = 0; hh < 2; hh++) {                                          \
        short8v pa_ = mk8(pk2bf(p[2*hh][0],   p[2*hh][1]),                    \
                          pk2bf(p[2*hh][2],   p[2*hh][3]),                    \
                          pk2bf(p[2*hh+1][0], p[2*hh+1][1]),                  \
                          pk2bf(p[2*hh+1][2], p[2*hh+1][3]));                 \
        _Pragma("unroll")                                                     \
        for (int db = 0; db < 4; db++) {                                      \
            const int drow_ = db*16 + lx;                                     \
            short8v bv_ = *(const short8v*)((char*)Vs + drow_*128 +           \
                                    ((16*lg + 64*hh) ^ ((drow_ & 7) << 4)));  \
            o_acc[db] = __builtin_amdgcn_mfma_f32_16x16x32_bf16(bv_, pa_,     \
                                                          o_acc[db], 0, 0, 0);\
        }                                                                     \
    }                                                                         \
    __builtin_amdgcn_s_setprio(0);                                            \
} while(0)

    const int t0 = half * 16, t1 = t0 + 16;
    STAGE_REGS(t0);
    WRITE_LDS();
    __syncthreads();

    for (int kt = t0; kt < t1; kt++) {
        const int kn = (kt+1 < t1) ? (kt+1) : kt;
        STAGE_REGS(kn);                // issue next tile's loads early (T14)
        COMPUTE(kt*64);
        __syncthreads();               // all reads of single buffer done
        WRITE_LDS();
        __syncthreads();               // writes visible
    }

#undef STAGE_REGS
#undef WRITE_LDS
#undef COMPUTE

    // epilogue: UNNORMALIZED partial O (bf16) + (m, l)
    {
        u16* op = (half ? O1 : O0) + (bh + q_glob)*HD + lg*4;
        #pragma unroll
        for (int db = 0; db < 4; db++) {
            uint2 ow;
            ow.x = pk2bf(o_acc[db][0], o_acc[db][1]);
            ow.y = pk2bf(o_acc[db][2], o_acc[db][3]);
            *(uint2*)(op + db*16) = ow;
        }
        if (lg == 0) {
            Mp[half*NROW + bh + q_glob] = m_i;
            Lp[half*NROW + bh + q_glob] = l_i;
        }
    }
}

// ---------------------------------------------------------------------------
// Merge split-K halves: O = (O0*2^(m0-m) + O1*2^(m1-m)) / (l0*2^(m0-m)+l1*2^(m1-m))
// Output AO in (B,nh,S,hd) bf16 -> written to AOout in (B,S,H) layout.
// ---------------------------------------------------------------------------
__global__ __launch_bounds__(256) void attn_merge(
    const u16* __restrict__ O0, const u16* __restrict__ O1,
    const float* __restrict__ Mp, const float* __restrict__ Lp,
    u16* __restrict__ AO)
{
    const int idx8 = (blockIdx.x*256 + threadIdx.x) * 8;   // (B,S,H) offset
    const int b   = idx8 / (S_LEN*HID);
    const int rem = idx8 - b*(S_LEN*HID);
    const int s   = rem / HID;
    const int hd  = rem - s*HID;
    const int hh  = hd >> 6;
    const int d0  = hd & 63;
    const int row = (b*NH + hh)*S_LEN + s;

    const float m0 = Mp[row], m1 = Mp[NROW + row];
    const float l0 = Lp[row], l1 = Lp[NROW + row];
    const float m  = fmaxf(m0, m1);
    const float w0 = exp2_fast(m0 - m);
    const float w1 = exp2_fast(m1 - m);
    const float inv = 1.f / (l0*w0 + l1*w1);

    const size_t ioff = (size_t)row*HD + d0;
    uint4 a = *(const uint4*)(O0 + ioff);
    uint4 c = *(const uint4*)(O1 + ioff);
    const u16* ap = (const u16*)&a;
    const u16* cp = (const u16*)&c;
    unsigned ow[4];
    #pragma unroll
    for (int j = 0; j < 4; j++) {
        float f0 = (bf2f(ap[2*j])*w0   + bf2f(cp[2*j])*w1)   * inv;
        float f1 = (bf2f(ap[2*j+1])*w0 + bf2f(cp[2*j+1])*w1) * inv;
        ow[j] = pk2bf(f0, f1);
    }
    uint4 o; o.x=ow[0]; o.y=ow[1]; o.z=ow[2]; o.w=ow[3];
    *(uint4*)(AO + idx8) = o;
}

// ---------------------------------------------------------------------------
extern "C" void kernel_launch(void* const* d_in, const int* in_sizes, int n_in,
                              void* d_out, int out_size, void* d_ws, size_t ws_size,
                              hipStream_t stream)
{
    const float* hidden = (const float*)d_in[0];
    const int*   amask  = (const int*)d_in[1];
    const int*   gmask  = (const int*)d_in[2];
    const float* Wq = (const float*)d_in[3];
    const float* bq = (const float*)d_in[4];
    const float* Wk = (const float*)d_in[5];
    const float* bk = (const float*)d_in[6];
    const float* Wv = (const float*)d_in[7];
    const float* bv = (const float*)d_in[8];
    const float* Wo = (const float*)d_in[9];
    const float* bo = (const float*)d_in[10];
    float* out = (float*)d_out;

    char* ws = (char*)d_ws;
    const size_t NTOK = (size_t)2 * S_LEN * HID;   // 3,145,728
    u16* hbf   = (u16*)(ws);                       // hidden bf16; later O1 partial
    u16* w4    = (u16*)(ws + 6291456);             // Wq',Wk,Wv,Wo bf16
    float* Mp  = (float*)(ws + 6291456);           // overlays Wq slice post-QKV
    float* Lp  = Mp + 2*NROW;
    u16* qkvbf = (u16*)(ws + 11010048);            // Q, K (2 x NTOK)
    u16* vtbf  = (u16*)(ws + 29884416);            // Vt; later merged AO (B,S,H)
    u16* aobf  = (u16*)(ws + 36175872);            // O0 partial

    convert_inputs<<<dim3(1536, 5), 256, 0, stream>>>(hidden, Wq, Wk, Wv, Wo, hbf, w4);

    gemm_mfma<<<dim3(32, 6, 3), 256, 0, stream>>>(hbf, w4, bq, bk, bv, qkvbf, vtbf, nullptr, 0);

    u16* Qbf = qkvbf;
    u16* Kbf = qkvbf + NTOK;

    attn_split<<<dim3(1536), 256, 0, stream>>>(Qbf, Kbf, vtbf, amask, gmask,
                                               aobf, hbf, Mp, Lp);

    attn_merge<<<dim3(1536), 256, 0, stream>>>(aobf, hbf, Mp, Lp, vtbf);

    gemm_mfma<<<dim3(32, 6), 256, 0, stream>>>(vtbf, w4, bo, nullptr, nullptr, nullptr, nullptr, out, 1);
}